// Round 4
// baseline (390.992 us; speedup 1.0000x reference)
//
#include <hip/hip_runtime.h>
#include <hip/hip_bf16.h>

// GapModel: per-env species-masked cosine-kernel^2 energy + segment sum.
// per_row[n] = (1/||ps_n||^2) * sum_m w[s_n,m] * (ps_n . sp[s_n,m])^2
// energy[t] = sum_{n: sid[n]==t} per_row[n]
//
// R6: counted-vmcnt deep pipeline (T3/T4) + bf16 A.
//  - prep kernel: ps -> bf16 copy (psb) + exact fp32 invnorm (invn).
//  - gemm: 4-buffer LDS for A, stage issued 2 steps ahead via global_load_lds,
//    B frags register-double-buffered 1 step ahead, ONE raw s_barrier per step,
//    counted s_waitcnt vmcnt(N) (never 0 in loop). Full 16-step unroll.
//  - fallback to R5 kernel if workspace too small for psb.

constexpr int kNEnv     = 100000;
constexpr int kDPS      = 512;
constexpr int kNSpecies = 4;
constexpr int kNSupport = 256;
constexpr int kCap      = 32768;

constexpr int BN = 64;
constexpr int BK = 32;

typedef __attribute__((ext_vector_type(8))) short short8;
typedef __attribute__((ext_vector_type(4))) float f32x4;

__device__ __forceinline__ short8 pack_bf16x8(const float4& a, const float4& b) {
  union { short8 v; __hip_bfloat162 h[4]; } u;
  u.h[0] = __float22bfloat162_rn({a.x, a.y});
  u.h[1] = __float22bfloat162_rn({a.z, a.w});
  u.h[2] = __float22bfloat162_rn({b.x, b.y});
  u.h[3] = __float22bfloat162_rn({b.z, b.w});
  return u.v;
}

__device__ __forceinline__ void gload_lds16(const void* g, void* l) {
  __builtin_amdgcn_global_load_lds(
      (const __attribute__((address_space(1))) void*)g,
      (__attribute__((address_space(3))) void*)l, 16, 0, 0);
}

// ---------------- species bucket scatter (ballot-rank) + B fp32->bf16 --------
__global__ void scatter_convert_kernel(const float* __restrict__ sp,
                                       const int* __restrict__ species,
                                       const int* __restrict__ sid,
                                       int* __restrict__ cnt, int* __restrict__ perm,
                                       int* __restrict__ sidp, short* __restrict__ spb) {
  const int t = threadIdx.x;
  const int b = blockIdx.x;
  if (b < (kNSpecies * kNSupport * kDPS) / (256 * 8)) {
    const int base = (b * 256 + t) * 8;
    const float4 lo = *(const float4*)(sp + base);
    const float4 hi = *(const float4*)(sp + base + 4);
    *(short8*)(spb + base) = pack_bf16x8(lo, hi);
  }
  const int wv   = t >> 6;
  const int lane = t & 63;
  const int i    = b * 256 + t;
  const bool v   = i < kNEnv;
  int s = -1, g = 0;
  if (v) { s = species[i]; g = sid[i]; }

  unsigned long long m[kNSpecies];
  #pragma unroll
  for (int k = 0; k < kNSpecies; ++k) m[k] = __ballot(s == k);
  int r = 0;
  if (v) r = __popcll(m[s] & ((1ull << lane) - 1ull));

  __shared__ int wcnt[4][kNSpecies];
  __shared__ int wbase[4][kNSpecies];
  if (lane < kNSpecies) wcnt[wv][lane] = (int)__popcll(m[lane]);
  __syncthreads();
  if (t < kNSpecies) {
    const int k = t;
    const int tot = wcnt[0][k] + wcnt[1][k] + wcnt[2][k] + wcnt[3][k];
    int p = tot ? atomicAdd(&cnt[k], tot) : 0;
    #pragma unroll
    for (int wvi = 0; wvi < 4; ++wvi) { wbase[wvi][k] = p; p += wcnt[wvi][k]; }
  }
  __syncthreads();
  if (v) {
    const int d = s * kCap + wbase[wv][s] + r;
    perm[d] = i;
    sidp[d] = g;
  }
}

// ---------------- prep: ps -> bf16 + exact fp32 1/||ps||^2 -------------------
__global__ __launch_bounds__(256) void norm_convert_kernel(
    const float* __restrict__ ps, short* __restrict__ psb, float* __restrict__ invn) {
  const int wv   = threadIdx.x >> 6;
  const int lane = threadIdx.x & 63;
  const int row  = blockIdx.x * 4 + wv;
  if (row >= kNEnv) return;
  const float* src = ps + (size_t)row * kDPS + lane * 8;
  const float4 a = *(const float4*)(src);
  const float4 b = *(const float4*)(src + 4);
  float sq = a.x * a.x + a.y * a.y + a.z * a.z + a.w * a.w
           + b.x * b.x + b.y * b.y + b.z * b.z + b.w * b.w;
  sq += __shfl_xor(sq, 1, 64);
  sq += __shfl_xor(sq, 2, 64);
  sq += __shfl_xor(sq, 4, 64);
  sq += __shfl_xor(sq, 8, 64);
  sq += __shfl_xor(sq, 16, 64);
  sq += __shfl_xor(sq, 32, 64);
  *(short8*)(psb + (size_t)row * kDPS + lane * 8) = pack_bf16x8(a, b);
  if (lane == 0) invn[row] = 1.0f / sq;
}

// ---------------- R6 gemm: counted-vmcnt pipeline, bf16 A --------------------
__global__ __launch_bounds__(256, 3) void gap_gemm_v6(
    const short* __restrict__ psb, const short* __restrict__ spb,
    const float* __restrict__ w, const float* __restrict__ invn,
    const int* __restrict__ cnt, const int* __restrict__ perm,
    const int* __restrict__ sidp, float* __restrict__ energy) {
  const int s     = blockIdx.z;
  const int count = min(cnt[s], kCap);
  const int tile0 = blockIdx.x * BN;
  if (tile0 >= count) return;

  __shared__ short a_lds[4][BN * BK];  // 4 bufs x 4 KB
  __shared__ float red[4][BN];

  const int tid  = threadIdx.x;
  const int wv   = tid >> 6;
  const int lane = tid & 63;
  const int l15  = lane & 15;
  const int lq   = lane >> 4;

  // stage source: wave wv stages rows [wv*16, wv*16+16); lane -> row wv*16+(lane>>2),
  // 16B slot (lane&3). One gload_lds16 per wave per step (1024 B).
  {
  }
  const int srow = wv * 16 + (lane >> 2);
  int ge = tile0 + srow;
  ge = ge < count ? ge : count - 1;
  const short* s_src = psb + (size_t)perm[s * kCap + ge] * kDPS + (lane & 3) * 8;

  // B pointers (bf16, L2-hot) + epilogue weights; wave owns m quarter wv*64..+64
  const short* bptr[4];
  float wgt[4];
  const float* w_s = w + s * kNSupport;
  #pragma unroll
  for (int fj = 0; fj < 4; ++fj) {
    const int m = wv * 64 + fj * 16 + l15;
    bptr[fj] = spb + ((size_t)s * kNSupport + m) * kDPS + lq * 8;
    wgt[fj]  = w_s[m];
  }

  f32x4 acc[4][4];
  #pragma unroll
  for (int fi = 0; fi < 4; ++fi)
    #pragma unroll
    for (int fj = 0; fj < 4; ++fj) acc[fi][fj] = (f32x4)0.f;

  short8 bf0[4], bf1[4];  // register double buffer for B (static indexing)

#define STAGEV6(T) gload_lds16(s_src + (T) * BK, &a_lds[(T) & 3][wv * 512])
#define BLOADV6(T, BF) do {                                            \
    _Pragma("unroll")                                                  \
    for (int fj = 0; fj < 4; ++fj)                                     \
      BF[fj] = *(const short8*)(bptr[fj] + (T) * BK);                  \
  } while (0)
#define BODYV6(T, BF) do {                                             \
    short8 af[4];                                                      \
    _Pragma("unroll")                                                  \
    for (int fi = 0; fi < 4; ++fi)                                     \
      af[fi] = *(const short8*)&a_lds[(T) & 3][fi * 512 + l15 * 32 + lq * 8]; \
    _Pragma("unroll")                                                  \
    for (int fi = 0; fi < 4; ++fi)                                     \
      _Pragma("unroll")                                                \
      for (int fj = 0; fj < 4; ++fj)                                   \
        acc[fi][fj] = __builtin_amdgcn_mfma_f32_16x16x32_bf16(         \
            af[fi], BF[fj], acc[fi][fj], 0, 0, 0);                     \
  } while (0)

// One step: barrier; prefetch B(t+1) and stage(t+2); counted wait drains
// exactly stage(t); body reads LDS buf t&3 and consumes B(t) regs.
#define STEPV6(T, VN, BFCUR, BFNXT) do {                               \
    asm volatile("s_barrier" ::: "memory");                            \
    if ((T) + 1 < 16) BLOADV6((T) + 1, BFNXT);                         \
    if ((T) + 2 < 16) STAGEV6((T) + 2);                                \
    asm volatile("s_waitcnt vmcnt(" #VN ")" ::: "memory");             \
    BODYV6(T, BFCUR);                                                  \
  } while (0)

  // prologue: 2 stages + first B in flight
  STAGEV6(0);
  STAGEV6(1);
  BLOADV6(0, bf0);

  STEPV6(0,  10, bf0, bf1);
  STEPV6(1,  10, bf1, bf0);
  STEPV6(2,  10, bf0, bf1);
  STEPV6(3,  10, bf1, bf0);
  STEPV6(4,  10, bf0, bf1);
  STEPV6(5,  10, bf1, bf0);
  STEPV6(6,  10, bf0, bf1);
  STEPV6(7,  10, bf1, bf0);
  STEPV6(8,  10, bf0, bf1);
  STEPV6(9,  10, bf1, bf0);
  STEPV6(10, 10, bf0, bf1);
  STEPV6(11, 10, bf1, bf0);
  STEPV6(12, 10, bf0, bf1);
  STEPV6(13, 10, bf1, bf0);
  STEPV6(14,  9, bf0, bf1);
  STEPV6(15,  4, bf1, bf0);

#undef STEPV6
#undef BODYV6
#undef BLOADV6
#undef STAGEV6

  // epilogue: contrib_env = sum_m w_m * C[env][m]^2
  // C/D layout: col(m) = lane&15, row(env) = (lane>>4)*4 + reg
  #pragma unroll
  for (int fi = 0; fi < 4; ++fi) {
    #pragma unroll
    for (int r = 0; r < 4; ++r) {
      float p = 0.f;
      #pragma unroll
      for (int fj = 0; fj < 4; ++fj) {
        const float c = acc[fi][fj][r];
        p += c * c * wgt[fj];
      }
      p += __shfl_xor(p, 1, 64);
      p += __shfl_xor(p, 2, 64);
      p += __shfl_xor(p, 4, 64);
      p += __shfl_xor(p, 8, 64);
      if (l15 == 0) red[wv][fi * 16 + lq * 4 + r] = p;
    }
  }
  __syncthreads();
  if (tid < BN) {
    const float v = red[0][tid] + red[1][tid] + red[2][tid] + red[3][tid];
    const int g  = tile0 + tid;
    if (g < count) {
      const int arow = perm[s * kCap + g];
      atomicAdd(&energy[sidp[s * kCap + g]], v * invn[arow]);
    }
  }
}

// ---------------- R5 fallback gemm (fp32 A staged, in-loop norm) -------------
__global__ __launch_bounds__(256, 3) void gap_gemm_v5(
    const float* __restrict__ ps, const short* __restrict__ spb,
    const float* __restrict__ w, const int* __restrict__ cnt,
    const int* __restrict__ perm, const int* __restrict__ sidp,
    float* __restrict__ energy) {
  const int s     = blockIdx.z;
  const int count = min(cnt[s], kCap);
  const int tile0 = blockIdx.x * BN;
  if (tile0 >= count) return;

  __shared__ float a_lds[2][BN * BK];
  __shared__ float red[4][BN];
  __shared__ float sqs[BN];

  const int tid  = threadIdx.x;
  const int wv   = tid >> 6;
  const int lane = tid & 63;
  const int l15  = lane & 15;
  const int lq   = lane >> 4;

  const int sby = (((lane & 7) << 4) ^ ((lane >> 3) << 4));
  const float* ssrc[2];
  #pragma unroll
  for (int c = 0; c < 2; ++c) {
    int r  = wv * 16 + c * 8 + (lane >> 3);
    int ge = tile0 + r;
    ge = ge < count ? ge : count - 1;
    ssrc[c] = ps + (size_t)perm[s * kCap + ge] * kDPS + (sby >> 2);
  }
  const int dof0 = (wv * 16) * BK;
  const int dof1 = (wv * 16 + 8) * BK;

  const short* bptr[4];
  float wgt[4];
  const float* w_s = w + s * kNSupport;
  #pragma unroll
  for (int fj = 0; fj < 4; ++fj) {
    const int m = wv * 64 + fj * 16 + l15;
    bptr[fj] = spb + ((size_t)s * kNSupport + m) * kDPS + lq * 8;
    wgt[fj]  = w_s[m];
  }

  const int fswz = (l15 & 7) << 4;
  const int cb1  = (lq * 32) ^ fswz;
  const int cb2  = (lq * 32 + 16) ^ fswz;
  const int rowb = l15 * 128;

  f32x4 acc[4][4];
  #pragma unroll
  for (int fi = 0; fi < 4; ++fi)
    #pragma unroll
    for (int fj = 0; fj < 4; ++fj) acc[fi][fj] = (f32x4)0.f;
  float sq[4] = {0.f, 0.f, 0.f, 0.f};

#define STAGE5(BUF, K0) do {                                   \
    gload_lds16(ssrc[0] + (K0), &a_lds[BUF][dof0]);            \
    gload_lds16(ssrc[1] + (K0), &a_lds[BUF][dof1]);            \
  } while (0)
#define BODY5(BUF, K0) do {                                                     \
    short8 bfv[4];                                                              \
    _Pragma("unroll")                                                           \
    for (int fj = 0; fj < 4; ++fj) bfv[fj] = *(const short8*)(bptr[fj] + (K0)); \
    const char* abase = (const char*)&a_lds[BUF][0];                            \
    _Pragma("unroll")                                                           \
    for (int fi = 0; fi < 4; ++fi) {                                            \
      const float4 f1 = *(const float4*)(abase + fi * 2048 + rowb + cb1);       \
      const float4 f2 = *(const float4*)(abase + fi * 2048 + rowb + cb2);       \
      if (wv == 0)                                                              \
        sq[fi] += f1.x * f1.x + f1.y * f1.y + f1.z * f1.z + f1.w * f1.w         \
                + f2.x * f2.x + f2.y * f2.y + f2.z * f2.z + f2.w * f2.w;        \
      const short8 af = pack_bf16x8(f1, f2);                                    \
      _Pragma("unroll")                                                         \
      for (int fj = 0; fj < 4; ++fj)                                            \
        acc[fi][fj] =                                                           \
            __builtin_amdgcn_mfma_f32_16x16x32_bf16(af, bfv[fj], acc[fi][fj], 0, 0, 0); \
    }                                                                           \
  } while (0)

  STAGE5(0, 0);
  __syncthreads();

  #pragma unroll 1
  for (int kp = 0; kp < kDPS; kp += 2 * BK) {
    STAGE5(1, kp + BK);
    BODY5(0, kp);
    __syncthreads();
    if (kp + 2 * BK < kDPS) STAGE5(0, kp + 2 * BK);
    BODY5(1, kp + BK);
    __syncthreads();
  }

#undef STAGE5
#undef BODY5

  if (wv == 0) {
    #pragma unroll
    for (int fi = 0; fi < 4; ++fi) {
      float p = sq[fi];
      p += __shfl_xor(p, 16, 64);
      p += __shfl_xor(p, 32, 64);
      if (lane < 16) sqs[fi * 16 + lane] = p;
    }
  }

  #pragma unroll
  for (int fi = 0; fi < 4; ++fi) {
    #pragma unroll
    for (int r = 0; r < 4; ++r) {
      float p = 0.f;
      #pragma unroll
      for (int fj = 0; fj < 4; ++fj) {
        const float c = acc[fi][fj][r];
        p += c * c * wgt[fj];
      }
      p += __shfl_xor(p, 1, 64);
      p += __shfl_xor(p, 2, 64);
      p += __shfl_xor(p, 4, 64);
      p += __shfl_xor(p, 8, 64);
      if (l15 == 0) red[wv][fi * 16 + lq * 4 + r] = p;
    }
  }
  __syncthreads();
  if (tid < BN) {
    const float v = red[0][tid] + red[1][tid] + red[2][tid] + red[3][tid];
    const int g  = tile0 + tid;
    if (g < count) atomicAdd(&energy[sidp[s * kCap + g]], v / sqs[tid]);
  }
}

extern "C" void kernel_launch(void* const* d_in, const int* in_sizes, int n_in,
                              void* d_out, int out_size, void* d_ws, size_t ws_size,
                              hipStream_t stream) {
  const float* ps      = (const float*)d_in[0];
  const float* sp      = (const float*)d_in[1];
  const float* w       = (const float*)d_in[2];
  const int*   species = (const int*)d_in[3];
  const int*   sid     = (const int*)d_in[4];
  float* energy = (float*)d_out;

  char* wsb = (char*)d_ws;
  // layout: cnt(256) | perm(512K) | sidp(512K) | spb(1M) | invn(400K+pad) | psb(102.4M)
  constexpr size_t kOffPerm = 256;
  constexpr size_t kOffSidp = kOffPerm + (size_t)kNSpecies * kCap * 4;
  constexpr size_t kOffSpb  = kOffSidp + (size_t)kNSpecies * kCap * 4;
  constexpr size_t kOffInvn = kOffSpb + (size_t)kNSpecies * kNSupport * kDPS * 2;
  constexpr size_t kOffPsb  = (kOffInvn + (size_t)kNEnv * 4 + 255) & ~(size_t)255;
  constexpr size_t kWsNeed  = kOffPsb + (size_t)kNEnv * kDPS * 2;

  int*   cnt  = (int*)wsb;
  int*   perm = (int*)(wsb + kOffPerm);
  int*   sidp = (int*)(wsb + kOffSidp);
  short* spb  = (short*)(wsb + kOffSpb);
  float* invn = (float*)(wsb + kOffInvn);
  short* psb  = (short*)(wsb + kOffPsb);

  hipMemsetAsync(cnt, 0, 16, stream);
  hipMemsetAsync(energy, 0, out_size * sizeof(float), stream);

  scatter_convert_kernel<<<(kNEnv + 255) / 256, 256, 0, stream>>>(
      sp, species, sid, cnt, perm, sidp, spb);

  if (ws_size >= kWsNeed) {
    norm_convert_kernel<<<(kNEnv + 3) / 4, 256, 0, stream>>>(ps, psb, invn);
    dim3 grid(kCap / BN, 1, kNSpecies);
    gap_gemm_v6<<<grid, 256, 0, stream>>>(psb, spb, w, invn, cnt, perm, sidp, energy);
  } else {
    dim3 grid(kCap / BN, 1, kNSpecies);
    gap_gemm_v5<<<grid, 256, 0, stream>>>(ps, spb, w, cnt, perm, sidp, energy);
  }
}

// Round 5
// 348.237 us; speedup vs baseline: 1.1228x; 1.1228x over previous
//
#include <hip/hip_runtime.h>
#include <hip/hip_bf16.h>

// GapModel: per-env species-masked cosine-kernel^2 energy + segment sum.
// per_row[n] = (1/||ps_n||^2) * sum_m w[s_n,m] * (ps_n . sp[s_n,m])^2
// energy[t] = sum_{n: sid[n]==t} per_row[n]
//
// R7: single-pass fp32-A (R5 body) x counted-vmcnt deep pipeline (R6), race-fixed.
//  - A (gathered fp32 rows) staged into 4-buffer LDS via global_load_lds w=16,
//    issued 2 steps ahead; pre-swizzled source + swizzled ds_read (rule 21).
//  - B (bf16, pre-converted, L2-hot) register-double-buffered 1 step ahead.
//  - Per step: issue B(t+1); issue S(t+2); s_waitcnt vmcnt(N) [6/8.../8/6/0];
//    s_barrier; MFMA body. Wait BEFORE barrier => all waves' stage(t) complete
//    when any wave starts reading buffer t (cross-wave safe by construction).
//  - ||ps||^2 accumulated by wave 0 from the staged fp32 fragments (free).
//  - s_setprio(1) around MFMA cluster (T5; schedule has wave role diversity).

constexpr int kNEnv     = 100000;
constexpr int kDPS      = 512;
constexpr int kNSpecies = 4;
constexpr int kNSupport = 256;
constexpr int kCap      = 32768;

constexpr int BN = 64;
constexpr int BK = 32;

typedef __attribute__((ext_vector_type(8))) short short8;
typedef __attribute__((ext_vector_type(4))) float f32x4;

__device__ __forceinline__ short8 pack_bf16x8(const float4& a, const float4& b) {
  union { short8 v; __hip_bfloat162 h[4]; } u;
  u.h[0] = __float22bfloat162_rn({a.x, a.y});
  u.h[1] = __float22bfloat162_rn({a.z, a.w});
  u.h[2] = __float22bfloat162_rn({b.x, b.y});
  u.h[3] = __float22bfloat162_rn({b.z, b.w});
  return u.v;
}

__device__ __forceinline__ void gload_lds16(const void* g, void* l) {
  __builtin_amdgcn_global_load_lds(
      (const __attribute__((address_space(1))) void*)g,
      (__attribute__((address_space(3))) void*)l, 16, 0, 0);
}

// ---------------- species bucket scatter (ballot-rank) + B fp32->bf16 --------
__global__ void scatter_convert_kernel(const float* __restrict__ sp,
                                       const int* __restrict__ species,
                                       const int* __restrict__ sid,
                                       int* __restrict__ cnt, int* __restrict__ perm,
                                       int* __restrict__ sidp, short* __restrict__ spb) {
  const int t = threadIdx.x;
  const int b = blockIdx.x;
  if (b < (kNSpecies * kNSupport * kDPS) / (256 * 8)) {
    const int base = (b * 256 + t) * 8;
    const float4 lo = *(const float4*)(sp + base);
    const float4 hi = *(const float4*)(sp + base + 4);
    *(short8*)(spb + base) = pack_bf16x8(lo, hi);
  }
  const int wv   = t >> 6;
  const int lane = t & 63;
  const int i    = b * 256 + t;
  const bool v   = i < kNEnv;
  int s = -1, g = 0;
  if (v) { s = species[i]; g = sid[i]; }

  unsigned long long m[kNSpecies];
  #pragma unroll
  for (int k = 0; k < kNSpecies; ++k) m[k] = __ballot(s == k);
  int r = 0;
  if (v) r = __popcll(m[s] & ((1ull << lane) - 1ull));

  __shared__ int wcnt[4][kNSpecies];
  __shared__ int wbase[4][kNSpecies];
  if (lane < kNSpecies) wcnt[wv][lane] = (int)__popcll(m[lane]);
  __syncthreads();
  if (t < kNSpecies) {
    const int k = t;
    const int tot = wcnt[0][k] + wcnt[1][k] + wcnt[2][k] + wcnt[3][k];
    int p = tot ? atomicAdd(&cnt[k], tot) : 0;
    #pragma unroll
    for (int wvi = 0; wvi < 4; ++wvi) { wbase[wvi][k] = p; p += wcnt[wvi][k]; }
  }
  __syncthreads();
  if (v) {
    const int d = s * kCap + wbase[wv][s] + r;
    perm[d] = i;
    sidp[d] = g;
  }
}

// ---------------- R7 gemm ----------------------------------------------------
__global__ __launch_bounds__(256, 3) void gap_gemm_v7(
    const float* __restrict__ ps, const short* __restrict__ spb,
    const float* __restrict__ w, const int* __restrict__ cnt,
    const int* __restrict__ perm, const int* __restrict__ sidp,
    float* __restrict__ energy) {
  const int s     = blockIdx.z;
  const int count = min(cnt[s], kCap);
  const int tile0 = blockIdx.x * BN;
  if (tile0 >= count) return;

  __shared__ float a_lds[4][BN * BK];   // 4 bufs x 8 KB = 32 KB
  __shared__ float red[4][BN];
  __shared__ float sqs[BN];

  const int tid  = threadIdx.x;
  const int wv   = tid >> 6;
  const int lane = tid & 63;
  const int l15  = lane & 15;
  const int lq   = lane >> 4;

  // staging: wave wv stages rows [wv*16, wv*16+16) as 2 x 1KB gload_lds.
  // lane L -> row c*8 + (L>>3), phys 16B slot (L&7); source col pre-swizzled
  // by ^ ((row&7)<<4) so the swizzled ds_read below sees logical data.
  const int sby = ((lane & 7) << 4) ^ (((lane >> 3) & 7) << 4);
  const float* ssrc[2];
  #pragma unroll
  for (int c = 0; c < 2; ++c) {
    int r  = wv * 16 + c * 8 + (lane >> 3);
    int ge = tile0 + r;
    ge = ge < count ? ge : count - 1;
    ssrc[c] = ps + (size_t)perm[s * kCap + ge] * kDPS + (sby >> 2);
  }
  const int dof0 = (wv * 16) * BK;
  const int dof1 = (wv * 16 + 8) * BK;

  // B pointers (bf16, L2-hot) + epilogue weights; wave owns m quarter wv*64..+64
  const short* bptr[4];
  float wgt[4];
  const float* w_s = w + s * kNSupport;
  #pragma unroll
  for (int fj = 0; fj < 4; ++fj) {
    const int m = wv * 64 + fj * 16 + l15;
    bptr[fj] = spb + ((size_t)s * kNSupport + m) * kDPS + lq * 8;
    wgt[fj]  = w_s[m];
  }

  // fragment ds_read byte offsets: row fi*16+l15, col bytes lq*32 / lq*32+16,
  // each XOR'd with (row&7)<<4 = (l15&7)<<4  (conflict-floor verified)
  const int fswz = (l15 & 7) << 4;
  const int cb1  = (lq * 32) ^ fswz;
  const int cb2  = (lq * 32 + 16) ^ fswz;
  const int rowb = l15 * 128;

  f32x4 acc[4][4];
  #pragma unroll
  for (int fi = 0; fi < 4; ++fi)
    #pragma unroll
    for (int fj = 0; fj < 4; ++fj) acc[fi][fj] = (f32x4)0.f;
  float sq[4] = {0.f, 0.f, 0.f, 0.f};

  short8 bf0[4], bf1[4];  // register double buffer for B (static indexing)

#define STAGE7(T) do {                                                  \
    gload_lds16(ssrc[0] + (T) * BK, &a_lds[(T) & 3][dof0]);             \
    gload_lds16(ssrc[1] + (T) * BK, &a_lds[(T) & 3][dof1]);             \
  } while (0)
#define BLOAD7(T, BF) do {                                              \
    _Pragma("unroll")                                                   \
    for (int fj = 0; fj < 4; ++fj)                                      \
      BF[fj] = *(const short8*)(bptr[fj] + (T) * BK);                   \
  } while (0)
#define BODY7(T, BF) do {                                                       \
    const char* abase = (const char*)&a_lds[(T) & 3][0];                        \
    __builtin_amdgcn_s_setprio(1);                                              \
    _Pragma("unroll")                                                           \
    for (int fi = 0; fi < 4; ++fi) {                                            \
      const float4 f1 = *(const float4*)(abase + fi * 2048 + rowb + cb1);       \
      const float4 f2 = *(const float4*)(abase + fi * 2048 + rowb + cb2);       \
      if (wv == 0)                                                              \
        sq[fi] += f1.x * f1.x + f1.y * f1.y + f1.z * f1.z + f1.w * f1.w         \
                + f2.x * f2.x + f2.y * f2.y + f2.z * f2.z + f2.w * f2.w;        \
      const short8 af = pack_bf16x8(f1, f2);                                    \
      _Pragma("unroll")                                                         \
      for (int fj = 0; fj < 4; ++fj)                                            \
        acc[fi][fj] = __builtin_amdgcn_mfma_f32_16x16x32_bf16(                  \
            af, BF[fj], acc[fi][fj], 0, 0, 0);                                  \
    }                                                                           \
    __builtin_amdgcn_s_setprio(0);                                              \
  } while (0)

// Per step t: issue B(t+1) [4 vmem], issue S(t+2) [2 vmem], counted wait
// (guarantees S(t)+B(t) complete), barrier (publishes buffer t block-wide),
// then MFMA body. Never vmcnt(0) until the final step.
#define STEP7(T, VN, BFCUR, BFNXT) do {                                 \
    if ((T) + 1 < 16) BLOAD7((T) + 1, BFNXT);                           \
    if ((T) + 2 < 16) STAGE7((T) + 2);                                  \
    asm volatile("s_waitcnt vmcnt(" #VN ")" ::: "memory");              \
    __builtin_amdgcn_s_barrier();                                       \
    BODY7(T, BFCUR);                                                    \
  } while (0)

  // prologue: S(0) S(1) B(0) in flight
  STAGE7(0);
  STAGE7(1);
  BLOAD7(0, bf0);

  STEP7(0,  6, bf0, bf1);
  STEP7(1,  8, bf1, bf0);
  STEP7(2,  8, bf0, bf1);
  STEP7(3,  8, bf1, bf0);
  STEP7(4,  8, bf0, bf1);
  STEP7(5,  8, bf1, bf0);
  STEP7(6,  8, bf0, bf1);
  STEP7(7,  8, bf1, bf0);
  STEP7(8,  8, bf0, bf1);
  STEP7(9,  8, bf1, bf0);
  STEP7(10, 8, bf0, bf1);
  STEP7(11, 8, bf1, bf0);
  STEP7(12, 8, bf0, bf1);
  STEP7(13, 8, bf1, bf0);
  STEP7(14, 6, bf0, bf1);
  STEP7(15, 0, bf1, bf0);

#undef STEP7
#undef BODY7
#undef BLOAD7
#undef STAGE7

  // ||ps||^2: wave 0 covered rows fi*16+l15 at k-slices lq*8..; sum over lq
  if (wv == 0) {
    #pragma unroll
    for (int fi = 0; fi < 4; ++fi) {
      float p = sq[fi];
      p += __shfl_xor(p, 16, 64);
      p += __shfl_xor(p, 32, 64);
      if (lane < 16) sqs[fi * 16 + lane] = p;
    }
  }

  // epilogue: contrib_env = sum_m w_m * C[env][m]^2
  // C/D layout: col(m) = lane&15, row(env) = (lane>>4)*4 + reg
  #pragma unroll
  for (int fi = 0; fi < 4; ++fi) {
    #pragma unroll
    for (int r = 0; r < 4; ++r) {
      float p = 0.f;
      #pragma unroll
      for (int fj = 0; fj < 4; ++fj) {
        const float c = acc[fi][fj][r];
        p += c * c * wgt[fj];
      }
      p += __shfl_xor(p, 1, 64);
      p += __shfl_xor(p, 2, 64);
      p += __shfl_xor(p, 4, 64);
      p += __shfl_xor(p, 8, 64);
      if (l15 == 0) red[wv][fi * 16 + lq * 4 + r] = p;
    }
  }
  __syncthreads();
  if (tid < BN) {
    const float v = red[0][tid] + red[1][tid] + red[2][tid] + red[3][tid];
    const int g  = tile0 + tid;
    if (g < count) atomicAdd(&energy[sidp[s * kCap + g]], v / sqs[tid]);
  }
}

extern "C" void kernel_launch(void* const* d_in, const int* in_sizes, int n_in,
                              void* d_out, int out_size, void* d_ws, size_t ws_size,
                              hipStream_t stream) {
  const float* ps      = (const float*)d_in[0];
  const float* sp      = (const float*)d_in[1];
  const float* w       = (const float*)d_in[2];
  const int*   species = (const int*)d_in[3];
  const int*   sid     = (const int*)d_in[4];
  float* energy = (float*)d_out;

  char* wsb = (char*)d_ws;
  // layout: cnt(256) | perm(512K) | sidp(512K) | spb(1M)
  constexpr size_t kOffPerm = 256;
  constexpr size_t kOffSidp = kOffPerm + (size_t)kNSpecies * kCap * 4;
  constexpr size_t kOffSpb  = kOffSidp + (size_t)kNSpecies * kCap * 4;

  int*   cnt  = (int*)wsb;
  int*   perm = (int*)(wsb + kOffPerm);
  int*   sidp = (int*)(wsb + kOffSidp);
  short* spb  = (short*)(wsb + kOffSpb);

  hipMemsetAsync(cnt, 0, 16, stream);
  hipMemsetAsync(energy, 0, out_size * sizeof(float), stream);

  scatter_convert_kernel<<<(kNEnv + 255) / 256, 256, 0, stream>>>(
      sp, species, sid, cnt, perm, sidp, spb);

  dim3 grid(kCap / BN, 1, kNSpecies);  // (512, 1, 4); early-out past count
  gap_gemm_v7<<<grid, 256, 0, stream>>>(ps, spb, w, cnt, perm, sidp, energy);
}

// Round 6
// 337.608 us; speedup vs baseline: 1.1581x; 1.0315x over previous
//
#include <hip/hip_runtime.h>
#include <hip/hip_bf16.h>

// GapModel: per-env species-masked cosine-kernel^2 energy + segment sum.
// per_row[n] = (1/||ps_n||^2) * sum_m w[s_n,m] * (ps_n . sp[s_n,m])^2
// energy[t] = sum_{n: sid[n]==t} per_row[n]
//
// R8: reg-staged group pipeline (T14). The compiler sabotages global_load_lds
// pipelines with conservative vmcnt(0) (R5==R7 proved it); global->VGPR->LDS
// gets precise counted waits instead. 4 groups x 4 K-steps:
//   barrier; pack+sq+ds_write(group g from regs R)   // R loaded a group ago
//   lgkmcnt(0); barrier; issue loads(g+1)->R         // in flight during MFMA
//   4 x [BLOAD(t+1); ds_read afrags; 16 MFMA]        // bf16 LDS, no pack in loop
// Single 16 KB bf16 A-buffer; wave b128 read/write patterns cover contiguous
// 1 KB bijectively -> structurally conflict-free (no swizzle).
// B (bf16, pre-converted) global->reg double-buffered, L2-hot.

constexpr int kNEnv     = 100000;
constexpr int kDPS      = 512;
constexpr int kNSpecies = 4;
constexpr int kNSupport = 256;
constexpr int kCap      = 32768;

constexpr int BN = 64;
constexpr int BK = 32;   // one MFMA K-step; 16 steps = 4 groups of 4

typedef __attribute__((ext_vector_type(8))) short short8;
typedef __attribute__((ext_vector_type(4))) float f32x4;

__device__ __forceinline__ short8 pack_bf16x8(const float4& a, const float4& b) {
  union { short8 v; __hip_bfloat162 h[4]; } u;
  u.h[0] = __float22bfloat162_rn({a.x, a.y});
  u.h[1] = __float22bfloat162_rn({a.z, a.w});
  u.h[2] = __float22bfloat162_rn({b.x, b.y});
  u.h[3] = __float22bfloat162_rn({b.z, b.w});
  return u.v;
}

// ---------------- species bucket scatter (ballot-rank) + B fp32->bf16 --------
__global__ void scatter_convert_kernel(const float* __restrict__ sp,
                                       const int* __restrict__ species,
                                       const int* __restrict__ sid,
                                       int* __restrict__ cnt, int* __restrict__ perm,
                                       int* __restrict__ sidp, short* __restrict__ spb) {
  const int t = threadIdx.x;
  const int b = blockIdx.x;
  if (b < (kNSpecies * kNSupport * kDPS) / (256 * 8)) {
    const int base = (b * 256 + t) * 8;
    const float4 lo = *(const float4*)(sp + base);
    const float4 hi = *(const float4*)(sp + base + 4);
    *(short8*)(spb + base) = pack_bf16x8(lo, hi);
  }
  const int wv   = t >> 6;
  const int lane = t & 63;
  const int i    = b * 256 + t;
  const bool v   = i < kNEnv;
  int s = -1, g = 0;
  if (v) { s = species[i]; g = sid[i]; }

  unsigned long long m[kNSpecies];
  #pragma unroll
  for (int k = 0; k < kNSpecies; ++k) m[k] = __ballot(s == k);
  int r = 0;
  if (v) r = __popcll(m[s] & ((1ull << lane) - 1ull));

  __shared__ int wcnt[4][kNSpecies];
  __shared__ int wbase[4][kNSpecies];
  if (lane < kNSpecies) wcnt[wv][lane] = (int)__popcll(m[lane]);
  __syncthreads();
  if (t < kNSpecies) {
    const int k = t;
    const int tot = wcnt[0][k] + wcnt[1][k] + wcnt[2][k] + wcnt[3][k];
    int p = tot ? atomicAdd(&cnt[k], tot) : 0;
    #pragma unroll
    for (int wvi = 0; wvi < 4; ++wvi) { wbase[wvi][k] = p; p += wcnt[wvi][k]; }
  }
  __syncthreads();
  if (v) {
    const int d = s * kCap + wbase[wv][s] + r;
    perm[d] = i;
    sidp[d] = g;
  }
}

// ---------------- R8 gemm ----------------------------------------------------
__global__ __launch_bounds__(256, 3) void gap_gemm_v8(
    const float* __restrict__ ps, const short* __restrict__ spb,
    const float* __restrict__ w, const int* __restrict__ cnt,
    const int* __restrict__ perm, const int* __restrict__ sidp,
    float* __restrict__ energy) {
  const int s     = blockIdx.z;
  const int count = min(cnt[s], kCap);
  const int tile0 = blockIdx.x * BN;
  if (tile0 >= count) return;

  __shared__ short a_lds[4][BN][32];   // [step][row][32 bf16] = 16 KB, 1 buffer
  __shared__ float red[4][BN];
  __shared__ float sqs[BN];

  const int tid  = threadIdx.x;
  const int wv   = tid >> 6;
  const int lane = tid & 63;
  const int l15  = lane & 15;
  const int lq   = lane >> 4;

  // staging assignment: lane covers row r0 = wv*16 + (lane>>2), fp32 quarter
  // q = lane&3 (8 floats per step). Per group: 8 float4 loads = 128 B/lane.
  const int r0 = wv * 16 + (lane >> 2);
  const int q  = lane & 3;
  int ge = tile0 + r0;
  ge = ge < count ? ge : count - 1;
  const float* asrc = ps + (size_t)perm[s * kCap + ge] * kDPS + q * 8;

  // B pointers (bf16, L2-hot) + epilogue weights; wave owns m quarter wv*64..+64
  const short* bptr[4];
  float wgt[4];
  const float* w_s = w + s * kNSupport;
  #pragma unroll
  for (int fj = 0; fj < 4; ++fj) {
    const int m = wv * 64 + fj * 16 + l15;
    bptr[fj] = spb + ((size_t)s * kNSupport + m) * kDPS + lq * 8;
    wgt[fj]  = w_s[m];
  }

  f32x4 acc[4][4];
  #pragma unroll
  for (int fi = 0; fi < 4; ++fi)
    #pragma unroll
    for (int fj = 0; fj < 4; ++fj) acc[fi][fj] = (f32x4)0.f;
  float sq = 0.f;

  float4 R[8];            // one group of A in flight (static indexing only)
  short8 bf0[4], bf1[4];  // B register double buffer

#define GLOAD8(G) do {                                                    \
    _Pragma("unroll")                                                     \
    for (int u = 0; u < 8; ++u)                                           \
      R[u] = *(const float4*)(asrc + (G) * 128 + (u >> 1) * 32 + (u & 1) * 4); \
  } while (0)

#define AWRITE8() do {                                                    \
    _Pragma("unroll")                                                     \
    for (int j = 0; j < 4; ++j) {                                         \
      const float4 va = R[2 * j], vb = R[2 * j + 1];                      \
      sq += va.x * va.x + va.y * va.y + va.z * va.z + va.w * va.w         \
          + vb.x * vb.x + vb.y * vb.y + vb.z * vb.z + vb.w * vb.w;        \
      *(short8*)&a_lds[j][r0][q * 8] = pack_bf16x8(va, vb);               \
    }                                                                     \
  } while (0)

#define BLOAD8(T, BF) do {                                                \
    _Pragma("unroll")                                                     \
    for (int fj = 0; fj < 4; ++fj)                                        \
      BF[fj] = *(const short8*)(bptr[fj] + (T) * BK);                     \
  } while (0)

#define ASTEP8(J, BF) do {                                                \
    short8 af[4];                                                         \
    _Pragma("unroll")                                                     \
    for (int fi = 0; fi < 4; ++fi)                                        \
      af[fi] = *(const short8*)&a_lds[J][fi * 16 + l15][lq * 8];          \
    __builtin_amdgcn_s_setprio(1);                                        \
    _Pragma("unroll")                                                     \
    for (int fi = 0; fi < 4; ++fi)                                        \
      _Pragma("unroll")                                                   \
      for (int fj = 0; fj < 4; ++fj)                                      \
        acc[fi][fj] = __builtin_amdgcn_mfma_f32_16x16x32_bf16(            \
            af[fi], BF[fj], acc[fi][fj], 0, 0, 0);                        \
    __builtin_amdgcn_s_setprio(0);                                        \
  } while (0)

// One group: publish LDS from regs, kick next group's loads, 4 MFMA steps.
// T = G*4. Compiler emits a COUNTED vmcnt before AWRITE (R is a register
// dest, precise tracking) -- loads were issued a full group earlier => free.
#define GROUP8(G) do {                                                    \
    __builtin_amdgcn_s_barrier();             /* WAR: prior reads done */ \
    AWRITE8();                                                            \
    asm volatile("s_waitcnt lgkmcnt(0)" ::: "memory");                    \
    __builtin_amdgcn_s_barrier();             /* publish buffer */        \
    __builtin_amdgcn_sched_barrier(0);                                    \
    if ((G) < 3) GLOAD8((G) + 1);             /* in flight over compute */\
    __builtin_amdgcn_sched_barrier(0);                                    \
    BLOAD8((G) * 4 + 1, bf1); ASTEP8(0, bf0);                             \
    BLOAD8((G) * 4 + 2, bf0); ASTEP8(1, bf1);                             \
    BLOAD8((G) * 4 + 3, bf1); ASTEP8(2, bf0);                             \
    if ((G) < 3) BLOAD8((G) * 4 + 4, bf0);                                \
    ASTEP8(3, bf1);                                                       \
  } while (0)

  GLOAD8(0);
  BLOAD8(0, bf0);
  GROUP8(0);
  GROUP8(1);
  GROUP8(2);
  GROUP8(3);

#undef GROUP8
#undef ASTEP8
#undef BLOAD8
#undef AWRITE8
#undef GLOAD8

  // ||ps||^2: reduce the 4 q-lanes of each row's quad; lane q==0 writes row r0
  sq += __shfl_xor(sq, 1, 64);
  sq += __shfl_xor(sq, 2, 64);
  if (q == 0) sqs[r0] = sq;

  // epilogue: contrib_env = sum_m w_m * C[env][m]^2
  // C/D layout: col(m) = lane&15, row(env) = (lane>>4)*4 + reg
  #pragma unroll
  for (int fi = 0; fi < 4; ++fi) {
    #pragma unroll
    for (int r = 0; r < 4; ++r) {
      float p = 0.f;
      #pragma unroll
      for (int fj = 0; fj < 4; ++fj) {
        const float c = acc[fi][fj][r];
        p += c * c * wgt[fj];
      }
      p += __shfl_xor(p, 1, 64);
      p += __shfl_xor(p, 2, 64);
      p += __shfl_xor(p, 4, 64);
      p += __shfl_xor(p, 8, 64);
      if (l15 == 0) red[wv][fi * 16 + lq * 4 + r] = p;
    }
  }
  __syncthreads();
  if (tid < BN) {
    const float v = red[0][tid] + red[1][tid] + red[2][tid] + red[3][tid];
    const int g  = tile0 + tid;
    if (g < count) atomicAdd(&energy[sidp[s * kCap + g]], v / sqs[tid]);
  }
}

extern "C" void kernel_launch(void* const* d_in, const int* in_sizes, int n_in,
                              void* d_out, int out_size, void* d_ws, size_t ws_size,
                              hipStream_t stream) {
  const float* ps      = (const float*)d_in[0];
  const float* sp      = (const float*)d_in[1];
  const float* w       = (const float*)d_in[2];
  const int*   species = (const int*)d_in[3];
  const int*   sid     = (const int*)d_in[4];
  float* energy = (float*)d_out;

  char* wsb = (char*)d_ws;
  // layout: cnt(256) | perm(512K) | sidp(512K) | spb(1M)
  constexpr size_t kOffPerm = 256;
  constexpr size_t kOffSidp = kOffPerm + (size_t)kNSpecies * kCap * 4;
  constexpr size_t kOffSpb  = kOffSidp + (size_t)kNSpecies * kCap * 4;

  int*   cnt  = (int*)wsb;
  int*   perm = (int*)(wsb + kOffPerm);
  int*   sidp = (int*)(wsb + kOffSidp);
  short* spb  = (short*)(wsb + kOffSpb);

  hipMemsetAsync(cnt, 0, 16, stream);
  hipMemsetAsync(energy, 0, out_size * sizeof(float), stream);

  scatter_convert_kernel<<<(kNEnv + 255) / 256, 256, 0, stream>>>(
      sp, species, sid, cnt, perm, sidp, spb);

  dim3 grid(kCap / BN, 1, kNSpecies);  // (512, 1, 4); early-out past count
  gap_gemm_v8<<<grid, 256, 0, stream>>>(ps, spb, w, cnt, perm, sidp, energy);
}